// Round 1
// baseline (469.637 us; speedup 1.0000x reference)
//
#include <hip/hip_runtime.h>

#define NCAT 32
#define NTOK 512
#define HID  512
#define EMB  1024
#define DSTATE 192

// ws layout:
//   [0,128)              int cnt[32]
//   [256, 256+65536)     int toklist[32][512]
//   [65792, +4 MiB)      float H[512 tokens][4 mods][512]

__global__ void bucket_kernel(const int* __restrict__ ids,
                              int* __restrict__ cnt,
                              int* __restrict__ toklist) {
    const int t = threadIdx.x;
    if (t < NCAT) cnt[t] = 0;
    __syncthreads();
    if (t < NTOK) {
        const int c = ids[t];
        const int pos = atomicAdd(&cnt[c], 1);
        toklist[c * NTOK + pos] = t;
    }
}

__global__ __launch_bounds__(256) void layer1_kernel(
    const float* __restrict__ state,
    const int* __restrict__ cnt, const int* __restrict__ toklist,
    const float* __restrict__ W1_0, const float* __restrict__ W1_1,
    const float* __restrict__ W1_2, const float* __restrict__ W1_3,
    const float* __restrict__ b1_0, const float* __restrict__ b1_1,
    const float* __restrict__ b1_2, const float* __restrict__ b1_3,
    float* __restrict__ H)
{
    const int cat = blockIdx.x, mod = blockIdx.y, chunk = blockIdx.z;
    const int nC = cnt[cat];
    const int start = chunk * 16;
    int nThis = nC - start;
    if (nThis <= 0) return;
    if (nThis > 16) nThis = 16;
    const int tid = threadIdx.x;

    __shared__ float sX[16 * 64];
    __shared__ int sTok[16];
    if (tid < nThis) sTok[tid] = toklist[cat * NTOK + start + tid];
    __syncthreads();

    const int L      = (mod < 2) ? 64 : 32;
    const int lshift = (mod < 2) ? 6 : 5;
    const int off    = (mod == 0) ? 0 : (mod == 1) ? 64 : (mod == 2) ? 128 : 160;

    for (int idx = tid; idx < (nThis << lshift); idx += 256) {
        const int t = idx >> lshift, e = idx & (L - 1);
        sX[t * L + e] = state[sTok[t] * DSTATE + off + e];
    }
    __syncthreads();

    const float* W1 = (mod == 0) ? W1_0 : (mod == 1) ? W1_1 : (mod == 2) ? W1_2 : W1_3;
    const float* b1 = (mod == 0) ? b1_0 : (mod == 1) ? b1_1 : (mod == 2) ? b1_2 : b1_3;
    const float* Wbase = W1 + cat * L * HID + 2 * tid;   // thread owns cols 2*tid, 2*tid+1

    float ax[16], ay[16];
#pragma unroll
    for (int t = 0; t < 16; ++t) { ax[t] = 0.f; ay[t] = 0.f; }

    const int nk4 = L >> 2;
    for (int k4 = 0; k4 < nk4; ++k4) {
        const float* p = Wbase + (k4 * 4) * HID;
        const float w0x = p[0],         w0y = p[1];
        const float w1x = p[HID],       w1y = p[HID + 1];
        const float w2x = p[2 * HID],   w2y = p[2 * HID + 1];
        const float w3x = p[3 * HID],   w3y = p[3 * HID + 1];
#pragma unroll
        for (int t = 0; t < 16; ++t) {
            if (t >= nThis) break;
            const float4 x4 = ((const float4*)(sX + t * L))[k4];
            ax[t] += x4.x * w0x + x4.y * w1x + x4.z * w2x + x4.w * w3x;
            ay[t] += x4.x * w0y + x4.y * w1y + x4.z * w2y + x4.w * w3y;
        }
    }

    const float bx = b1[cat * HID + 2 * tid];
    const float by = b1[cat * HID + 2 * tid + 1];
#pragma unroll
    for (int t = 0; t < 16; ++t) {
        if (t >= nThis) break;
        float hx = ax[t] + bx; hx = hx > 0.f ? hx : 0.f;
        float hy = ay[t] + by; hy = hy > 0.f ? hy : 0.f;
        *(float2*)(H + (sTok[t] * 4 + mod) * HID + 2 * tid) = make_float2(hx, hy);
    }
}

__global__ __launch_bounds__(256) void layer2_kernel(
    const int* __restrict__ cnt, const int* __restrict__ toklist,
    const float* __restrict__ H,
    const float* __restrict__ W2_0, const float* __restrict__ W2_1,
    const float* __restrict__ W2_2, const float* __restrict__ W2_3,
    const float* __restrict__ b2_0, const float* __restrict__ b2_1,
    const float* __restrict__ b2_2, const float* __restrict__ b2_3,
    const float* __restrict__ te_0, const float* __restrict__ te_1,
    const float* __restrict__ te_2, const float* __restrict__ te_3,
    float* __restrict__ out)
{
    const int cat = blockIdx.x, mod = blockIdx.y;
    const int coltile = blockIdx.z & 3, chunk = blockIdx.z >> 2;   // gridDim.z = 64
    const int nC = cnt[cat];
    const int start = chunk * 32;
    int nThis = nC - start;
    if (nThis <= 0) return;
    if (nThis > 32) nThis = 32;
    const int tid = threadIdx.x;

    __shared__ float sH[32 * 256];   // 32 KiB: half of K at a time
    __shared__ int sTok[32];
    if (tid < nThis) sTok[tid] = toklist[cat * NTOK + start + tid];

    const float* W2 = (mod == 0) ? W2_0 : (mod == 1) ? W2_1 : (mod == 2) ? W2_2 : W2_3;
    const float* b2 = (mod == 0) ? b2_0 : (mod == 1) ? b2_1 : (mod == 2) ? b2_2 : b2_3;
    const float* te = (mod == 0) ? te_0 : (mod == 1) ? te_1 : (mod == 2) ? te_2 : te_3;

    const int col = coltile * 256 + tid;
    const float* Wbase = W2 + cat * (HID * EMB) + col;

    float acc[32];
#pragma unroll
    for (int t = 0; t < 32; ++t) acc[t] = 0.f;

    for (int half = 0; half < 2; ++half) {
        __syncthreads();   // covers sTok->stage (half 0) and compute->restage (half 1)
        for (int idx = tid; idx < (nThis << 6); idx += 256) {   // nThis*64 float4s
            const int t = idx >> 6, e = idx & 63;
            ((float4*)sH)[t * 64 + e] =
                ((const float4*)(H + (sTok[t] * 4 + mod) * HID + half * 256))[e];
        }
        __syncthreads();

        const float* Wk = Wbase + (half * 256) * EMB;
#pragma unroll 2
        for (int k4 = 0; k4 < 64; ++k4) {
            const float* p = Wk + (k4 * 4) * EMB;
            const float w0 = p[0];
            const float w1 = p[EMB];
            const float w2 = p[2 * EMB];
            const float w3 = p[3 * EMB];
#pragma unroll
            for (int t = 0; t < 32; ++t) {
                if (t >= nThis) break;
                const float4 h4 = ((const float4*)sH)[t * 64 + k4];
                acc[t] += h4.x * w0 + h4.y * w1 + h4.z * w2 + h4.w * w3;
            }
        }
    }

    const float bias = b2[cat * EMB + col] + te[col];
#pragma unroll
    for (int t = 0; t < 32; ++t) {
        if (t >= nThis) break;
        out[(sTok[t] * 4 + mod) * EMB + col] = acc[t] + bias;
    }
}

extern "C" void kernel_launch(void* const* d_in, const int* in_sizes, int n_in,
                              void* d_out, int out_size, void* d_ws, size_t ws_size,
                              hipStream_t stream) {
    const float* state = (const float*)d_in[0];
    const int*   ids   = (const int*)d_in[1];
    const float *W1[4], *b1[4], *W2[4], *b2[4], *te[4];
    for (int m = 0; m < 4; ++m) {
        W1[m] = (const float*)d_in[2 + 5 * m + 0];
        b1[m] = (const float*)d_in[2 + 5 * m + 1];
        W2[m] = (const float*)d_in[2 + 5 * m + 2];
        b2[m] = (const float*)d_in[2 + 5 * m + 3];
        te[m] = (const float*)d_in[2 + 5 * m + 4];
    }
    char* ws = (char*)d_ws;
    int*   cnt     = (int*)ws;
    int*   toklist = (int*)(ws + 256);
    float* H       = (float*)(ws + 65792);
    float* out     = (float*)d_out;

    bucket_kernel<<<1, 512, 0, stream>>>(ids, cnt, toklist);
    layer1_kernel<<<dim3(32, 4, 32), 256, 0, stream>>>(
        state, cnt, toklist,
        W1[0], W1[1], W1[2], W1[3],
        b1[0], b1[1], b1[2], b1[3], H);
    layer2_kernel<<<dim3(32, 4, 64), 256, 0, stream>>>(
        cnt, toklist, H,
        W2[0], W2[1], W2[2], W2[3],
        b2[0], b2[1], b2[2], b2[3],
        te[0], te[1], te[2], te[3], out);
}

// Round 2
// 434.858 us; speedup vs baseline: 1.0800x; 1.0800x over previous
//
#include <hip/hip_runtime.h>

#define NCAT 32
#define NTOK 512
#define HID  512
#define EMB  1024
#define DSTATE 192

// ws layout:
//   [0,128)              int cnt[32]
//   [256, 256+65536)     int toklist[32][512]
//   [65792, +4 MiB)      float H[512 tokens][4 mods][512]

__global__ void bucket_kernel(const int* __restrict__ ids,
                              int* __restrict__ cnt,
                              int* __restrict__ toklist) {
    const int t = threadIdx.x;
    if (t < NCAT) cnt[t] = 0;
    __syncthreads();
    if (t < NTOK) {
        const int c = ids[t];
        const int pos = atomicAdd(&cnt[c], 1);
        toklist[c * NTOK + pos] = t;
    }
}

__global__ __launch_bounds__(256) void zero_out_kernel(float4* __restrict__ out) {
    out[blockIdx.x * 256 + threadIdx.x] = make_float4(0.f, 0.f, 0.f, 0.f);
}

// grid (32 cat, 4 mod, 16 chunk), 256 threads. 32 tokens/block (zero-padded),
// thread owns hid cols {2*tid, 2*tid+1}. No breaks -> acc stays in VGPRs.
__global__ __launch_bounds__(256, 2) void layer1_kernel(
    const float* __restrict__ state,
    const int* __restrict__ cnt, const int* __restrict__ toklist,
    const float* __restrict__ W1_0, const float* __restrict__ W1_1,
    const float* __restrict__ W1_2, const float* __restrict__ W1_3,
    const float* __restrict__ b1_0, const float* __restrict__ b1_1,
    const float* __restrict__ b1_2, const float* __restrict__ b1_3,
    float* __restrict__ H)
{
    const int cat = blockIdx.x, mod = blockIdx.y, chunk = blockIdx.z;
    const int nC = cnt[cat];
    const int start = chunk * 32;
    int nThis = nC - start;
    if (nThis <= 0) return;
    if (nThis > 32) nThis = 32;
    const int tid = threadIdx.x;

    const int L      = (mod < 2) ? 64 : 32;
    const int lf4    = L >> 2;                 // float4s per token row
    const int lsh    = (mod < 2) ? 4 : 3;      // log2(lf4)
    const int off    = (mod == 0) ? 0 : (mod == 1) ? 64 : (mod == 2) ? 128 : 160;

    __shared__ float sX[32 * 64];              // [t][L], zero-padded
    __shared__ int sTok[32];
    if (tid < 32) sTok[tid] = (tid < nThis) ? toklist[cat * NTOK + start + tid] : 0;
    __syncthreads();

    const int nf4 = 32 << lsh;                 // 32 * lf4
    for (int idx = tid; idx < nf4; idx += 256) {
        const int t = idx >> lsh, e = idx & (lf4 - 1);
        float4 v = make_float4(0.f, 0.f, 0.f, 0.f);
        if (t < nThis)
            v = ((const float4*)(state + sTok[t] * DSTATE + off))[e];
        ((float4*)sX)[t * lf4 + e] = v;        // row stride = lf4 f4s
    }
    __syncthreads();

    const float* W1 = (mod == 0) ? W1_0 : (mod == 1) ? W1_1 : (mod == 2) ? W1_2 : W1_3;
    const float* b1 = (mod == 0) ? b1_0 : (mod == 1) ? b1_1 : (mod == 2) ? b1_2 : b1_3;
    const float* Wcol = W1 + cat * L * HID + 2 * tid;

    float ax[32], ay[32];
#pragma unroll
    for (int t = 0; t < 32; ++t) { ax[t] = 0.f; ay[t] = 0.f; }

#pragma unroll 2
    for (int k4 = 0; k4 < lf4; ++k4) {
        const float* p = Wcol + (k4 * 4) * HID;
        const float2 w0 = *(const float2*)(p);
        const float2 w1 = *(const float2*)(p + HID);
        const float2 w2 = *(const float2*)(p + 2 * HID);
        const float2 w3 = *(const float2*)(p + 3 * HID);
#pragma unroll
        for (int t = 0; t < 32; ++t) {
            const float4 x4 = ((const float4*)sX)[t * lf4 + k4];
            ax[t] += x4.x * w0.x + x4.y * w1.x + x4.z * w2.x + x4.w * w3.x;
            ay[t] += x4.x * w0.y + x4.y * w1.y + x4.z * w2.y + x4.w * w3.y;
        }
    }

    const float bx = b1[cat * HID + 2 * tid];
    const float by = b1[cat * HID + 2 * tid + 1];
    for (int t = 0; t < nThis; ++t) {
        float hx = ax[t] + bx; hx = hx > 0.f ? hx : 0.f;
        float hy = ay[t] + by; hy = hy > 0.f ? hy : 0.f;
        *(float2*)(H + (sTok[t] * 4 + mod) * HID + 2 * tid) = make_float2(hx, hy);
    }
}

// grid (32 cat, 4 mod, z = chunk(16) x ks(4) x coltile(2) = 128), 256 threads.
// 32 tokens/block zero-padded, K-slice of 128, thread owns cols
// {coltile*512 + 2*tid, +1}. Partials atomicAdd'ed into zeroed out.
__global__ __launch_bounds__(256, 2) void layer2_kernel(
    const int* __restrict__ cnt, const int* __restrict__ toklist,
    const float* __restrict__ H,
    const float* __restrict__ W2_0, const float* __restrict__ W2_1,
    const float* __restrict__ W2_2, const float* __restrict__ W2_3,
    const float* __restrict__ b2_0, const float* __restrict__ b2_1,
    const float* __restrict__ b2_2, const float* __restrict__ b2_3,
    const float* __restrict__ te_0, const float* __restrict__ te_1,
    const float* __restrict__ te_2, const float* __restrict__ te_3,
    float* __restrict__ out)
{
    const int cat = blockIdx.x, mod = blockIdx.y;
    const int coltile = blockIdx.z & 1;
    const int ks      = (blockIdx.z >> 1) & 3;
    const int chunk   = blockIdx.z >> 3;
    const int nC = cnt[cat];
    const int start = chunk * 32;
    int nThis = nC - start;
    if (nThis <= 0) return;
    if (nThis > 32) nThis = 32;
    const int tid = threadIdx.x;

    __shared__ float sH[32 * 128];             // [t][k within slice], 16 KiB
    __shared__ int sTok[32];
    if (tid < 32) sTok[tid] = (tid < nThis) ? toklist[cat * NTOK + start + tid] : 0;
    __syncthreads();

    for (int idx = tid; idx < 32 * 32; idx += 256) {   // 1024 float4s
        const int t = idx >> 5, e = idx & 31;
        float4 v = make_float4(0.f, 0.f, 0.f, 0.f);
        if (t < nThis)
            v = ((const float4*)(H + (sTok[t] * 4 + mod) * HID + ks * 128))[e];
        ((float4*)sH)[idx] = v;
    }
    __syncthreads();

    const float* W2 = (mod == 0) ? W2_0 : (mod == 1) ? W2_1 : (mod == 2) ? W2_2 : W2_3;
    const float* b2 = (mod == 0) ? b2_0 : (mod == 1) ? b2_1 : (mod == 2) ? b2_2 : b2_3;
    const float* te = (mod == 0) ? te_0 : (mod == 1) ? te_1 : (mod == 2) ? te_2 : te_3;

    const int col = coltile * 512 + 2 * tid;
    const float* Wcol = W2 + cat * (HID * EMB) + (ks * 128) * EMB + col;

    float ax[32], ay[32];
#pragma unroll
    for (int t = 0; t < 32; ++t) { ax[t] = 0.f; ay[t] = 0.f; }

#pragma unroll 2
    for (int k4 = 0; k4 < 32; ++k4) {
        const float* p = Wcol + (k4 * 4) * EMB;
        const float2 w0 = *(const float2*)(p);
        const float2 w1 = *(const float2*)(p + EMB);
        const float2 w2 = *(const float2*)(p + 2 * EMB);
        const float2 w3 = *(const float2*)(p + 3 * EMB);
#pragma unroll
        for (int t = 0; t < 32; ++t) {
            const float4 h4 = ((const float4*)sH)[t * 32 + k4];
            ax[t] += h4.x * w0.x + h4.y * w1.x + h4.z * w2.x + h4.w * w3.x;
            ay[t] += h4.x * w0.y + h4.y * w1.y + h4.z * w2.y + h4.w * w3.y;
        }
    }

    float bx = 0.f, by = 0.f;
    if (ks == 0) {
        bx = b2[cat * EMB + col] + te[col];
        by = b2[cat * EMB + col + 1] + te[col + 1];
    }
    for (int t = 0; t < nThis; ++t) {
        float* o = out + (sTok[t] * 4 + mod) * EMB + col;
        atomicAdd(o,     ax[t] + bx);
        atomicAdd(o + 1, ay[t] + by);
    }
}

extern "C" void kernel_launch(void* const* d_in, const int* in_sizes, int n_in,
                              void* d_out, int out_size, void* d_ws, size_t ws_size,
                              hipStream_t stream) {
    const float* state = (const float*)d_in[0];
    const int*   ids   = (const int*)d_in[1];
    const float *W1[4], *b1[4], *W2[4], *b2[4], *te[4];
    for (int m = 0; m < 4; ++m) {
        W1[m] = (const float*)d_in[2 + 5 * m + 0];
        b1[m] = (const float*)d_in[2 + 5 * m + 1];
        W2[m] = (const float*)d_in[2 + 5 * m + 2];
        b2[m] = (const float*)d_in[2 + 5 * m + 3];
        te[m] = (const float*)d_in[2 + 5 * m + 4];
    }
    char* ws = (char*)d_ws;
    int*   cnt     = (int*)ws;
    int*   toklist = (int*)(ws + 256);
    float* H       = (float*)(ws + 65792);
    float* out     = (float*)d_out;

    bucket_kernel<<<1, 512, 0, stream>>>(ids, cnt, toklist);
    zero_out_kernel<<<2048, 256, 0, stream>>>((float4*)out);   // 2M floats
    layer1_kernel<<<dim3(32, 4, 16), 256, 0, stream>>>(
        state, cnt, toklist,
        W1[0], W1[1], W1[2], W1[3],
        b1[0], b1[1], b1[2], b1[3], H);
    layer2_kernel<<<dim3(32, 4, 128), 256, 0, stream>>>(
        cnt, toklist, H,
        W2[0], W2[1], W2[2], W2[3],
        b2[0], b2[1], b2[2], b2[3],
        te[0], te[1], te[2], te[3], out);
}

// Round 3
// 421.942 us; speedup vs baseline: 1.1130x; 1.0306x over previous
//
#include <hip/hip_runtime.h>

#define NCAT 32
#define NTOK 512
#define HID  512
#define EMB  1024
#define DSTATE 192

// ws layout:
//   [0,128)        int cnt[32]
//   [128,136)      int nW[2]        (nW[0]=layer1 chunks of 32, nW[1]=layer2 chunks of 16)
//   [256,512)      int work1[64]    entries: cat | (chunk<<8)
//   [512,768)      int work2[64]
//   [1024,66560)   int toklist[32][512]
//   [66560,+4MiB)  float H[512 tok][4 mod][512]

__global__ __launch_bounds__(512) void bucket_kernel(
    const int* __restrict__ ids, int* __restrict__ cnt, int* __restrict__ nW,
    int* __restrict__ work1, int* __restrict__ work2, int* __restrict__ toklist)
{
    __shared__ int scnt[NCAT];
    const int tid = threadIdx.x;
    if (tid < NCAT) scnt[tid] = 0;
    __syncthreads();
    const int c = ids[tid];                       // 512 threads == 512 tokens
    const int pos = atomicAdd(&scnt[c], 1);       // LDS atomic: cheap
    toklist[c * NTOK + pos] = tid;
    __syncthreads();
    if (tid == 0) {
        int n1 = 0, n2 = 0;
        for (int cc = 0; cc < NCAT; ++cc) {
            const int n = scnt[cc];
            cnt[cc] = n;
            for (int ch = 0; ch * 32 < n; ++ch) work1[n1++] = cc | (ch << 8);
            for (int ch = 0; ch * 16 < n; ++ch) work2[n2++] = cc | (ch << 8);
        }
        nW[0] = n1; nW[1] = n2;
    }
}

// grid (48 slots, 4 mod), 256 threads. 32 tokens/block zero-padded,
// thread owns hid cols {2*tid, 2*tid+1}.
__global__ __launch_bounds__(256, 2) void layer1_kernel(
    const float* __restrict__ state,
    const int* __restrict__ cnt, const int* __restrict__ toklist,
    const int* __restrict__ nW, const int* __restrict__ work1,
    const float* __restrict__ W1_0, const float* __restrict__ W1_1,
    const float* __restrict__ W1_2, const float* __restrict__ W1_3,
    const float* __restrict__ b1_0, const float* __restrict__ b1_1,
    const float* __restrict__ b1_2, const float* __restrict__ b1_3,
    float* __restrict__ H)
{
    const int slot = blockIdx.x, mod = blockIdx.y;
    if (slot >= nW[0]) return;
    const int ent = work1[slot];
    const int cat = ent & 255, chunk = ent >> 8;
    const int nC = cnt[cat];
    const int start = chunk * 32;
    int nThis = nC - start;
    if (nThis > 32) nThis = 32;
    const int tid = threadIdx.x;

    const int L   = (mod < 2) ? 64 : 32;
    const int lf4 = L >> 2;
    const int lsh = (mod < 2) ? 4 : 3;
    const int off = (mod == 0) ? 0 : (mod == 1) ? 64 : (mod == 2) ? 128 : 160;

    __shared__ float sX[32 * 64];
    __shared__ int sTok[32];
    if (tid < 32) sTok[tid] = (tid < nThis) ? toklist[cat * NTOK + start + tid] : 0;
    __syncthreads();

    const int nf4 = 32 << lsh;
    for (int idx = tid; idx < nf4; idx += 256) {
        const int t = idx >> lsh, e = idx & (lf4 - 1);
        float4 v = make_float4(0.f, 0.f, 0.f, 0.f);
        if (t < nThis)
            v = ((const float4*)(state + sTok[t] * DSTATE + off))[e];
        ((float4*)sX)[t * lf4 + e] = v;
    }
    __syncthreads();

    const float* W1 = (mod == 0) ? W1_0 : (mod == 1) ? W1_1 : (mod == 2) ? W1_2 : W1_3;
    const float* b1 = (mod == 0) ? b1_0 : (mod == 1) ? b1_1 : (mod == 2) ? b1_2 : b1_3;
    const float* Wcol = W1 + cat * L * HID + 2 * tid;

    float ax[32], ay[32];
#pragma unroll
    for (int t = 0; t < 32; ++t) { ax[t] = 0.f; ay[t] = 0.f; }

#pragma unroll 2
    for (int k4 = 0; k4 < lf4; ++k4) {
        const float* p = Wcol + (k4 * 4) * HID;
        const float2 w0 = *(const float2*)(p);
        const float2 w1 = *(const float2*)(p + HID);
        const float2 w2 = *(const float2*)(p + 2 * HID);
        const float2 w3 = *(const float2*)(p + 3 * HID);
#pragma unroll
        for (int t = 0; t < 32; ++t) {
            const float4 x4 = ((const float4*)sX)[t * lf4 + k4];
            ax[t] += x4.x * w0.x + x4.y * w1.x + x4.z * w2.x + x4.w * w3.x;
            ay[t] += x4.x * w0.y + x4.y * w1.y + x4.z * w2.y + x4.w * w3.y;
        }
    }

    const float bx = b1[cat * HID + 2 * tid];
    const float by = b1[cat * HID + 2 * tid + 1];
#pragma unroll
    for (int t = 0; t < 32; ++t) {
        if (t >= nThis) break;
        float hx = ax[t] + bx; hx = hx > 0.f ? hx : 0.f;
        float hy = ay[t] + by; hy = hy > 0.f ? hy : 0.f;
        *(float2*)(H + (sTok[t] * 4 + mod) * HID + 2 * tid) = make_float2(hx, hy);
    }
}

// grid (64 slots, 4 mod, 2 colhalf), 256 threads. 16 tokens/block zero-padded,
// full K=512 (no atomics), thread owns cols {colhalf*512+2*tid, +1}.
__global__ __launch_bounds__(256, 2) void layer2_kernel(
    const int* __restrict__ cnt, const int* __restrict__ toklist,
    const int* __restrict__ nW, const int* __restrict__ work2,
    const float* __restrict__ H,
    const float* __restrict__ W2_0, const float* __restrict__ W2_1,
    const float* __restrict__ W2_2, const float* __restrict__ W2_3,
    const float* __restrict__ b2_0, const float* __restrict__ b2_1,
    const float* __restrict__ b2_2, const float* __restrict__ b2_3,
    const float* __restrict__ te_0, const float* __restrict__ te_1,
    const float* __restrict__ te_2, const float* __restrict__ te_3,
    float* __restrict__ out)
{
    const int slot = blockIdx.x, mod = blockIdx.y, colhalf = blockIdx.z;
    if (slot >= nW[1]) return;
    const int ent = work2[slot];
    const int cat = ent & 255, chunk = ent >> 8;
    const int nC = cnt[cat];
    const int start = chunk * 16;
    int nThis = nC - start;
    if (nThis > 16) nThis = 16;
    const int tid = threadIdx.x;

    __shared__ float sH[16 * 512];             // 32 KiB, [t][k] zero-padded
    __shared__ int sTok[16];
    if (tid < 16) sTok[tid] = (tid < nThis) ? toklist[cat * NTOK + start + tid] : 0;
    __syncthreads();

    for (int idx = tid; idx < 16 * 128; idx += 256) {   // 2048 float4s
        const int t = idx >> 7, e4 = idx & 127;
        float4 v = make_float4(0.f, 0.f, 0.f, 0.f);
        if (t < nThis)
            v = ((const float4*)(H + (sTok[t] * 4 + mod) * HID))[e4];
        ((float4*)sH)[idx] = v;
    }
    __syncthreads();

    const float* W2 = (mod == 0) ? W2_0 : (mod == 1) ? W2_1 : (mod == 2) ? W2_2 : W2_3;
    const float* b2 = (mod == 0) ? b2_0 : (mod == 1) ? b2_1 : (mod == 2) ? b2_2 : b2_3;
    const float* te = (mod == 0) ? te_0 : (mod == 1) ? te_1 : (mod == 2) ? te_2 : te_3;

    const int col = colhalf * 512 + 2 * tid;
    const float* Wcol = W2 + cat * (HID * EMB) + col;

    float ax[16], ay[16];
#pragma unroll
    for (int t = 0; t < 16; ++t) { ax[t] = 0.f; ay[t] = 0.f; }

#pragma unroll 4
    for (int k4 = 0; k4 < 128; ++k4) {
        const float* p = Wcol + (k4 * 4) * EMB;
        const float2 w0 = *(const float2*)(p);
        const float2 w1 = *(const float2*)(p + EMB);
        const float2 w2 = *(const float2*)(p + 2 * EMB);
        const float2 w3 = *(const float2*)(p + 3 * EMB);
#pragma unroll
        for (int t = 0; t < 16; ++t) {
            const float4 h4 = ((const float4*)sH)[t * 128 + k4];
            ax[t] += h4.x * w0.x + h4.y * w1.x + h4.z * w2.x + h4.w * w3.x;
            ay[t] += h4.x * w0.y + h4.y * w1.y + h4.z * w2.y + h4.w * w3.y;
        }
    }

    const float bx = b2[cat * EMB + col] + te[col];
    const float by = b2[cat * EMB + col + 1] + te[col + 1];
#pragma unroll
    for (int t = 0; t < 16; ++t) {
        if (t >= nThis) break;
        *(float2*)(out + (sTok[t] * 4 + mod) * EMB + col) =
            make_float2(ax[t] + bx, ay[t] + by);
    }
}

extern "C" void kernel_launch(void* const* d_in, const int* in_sizes, int n_in,
                              void* d_out, int out_size, void* d_ws, size_t ws_size,
                              hipStream_t stream) {
    const float* state = (const float*)d_in[0];
    const int*   ids   = (const int*)d_in[1];
    const float *W1[4], *b1[4], *W2[4], *b2[4], *te[4];
    for (int m = 0; m < 4; ++m) {
        W1[m] = (const float*)d_in[2 + 5 * m + 0];
        b1[m] = (const float*)d_in[2 + 5 * m + 1];
        W2[m] = (const float*)d_in[2 + 5 * m + 2];
        b2[m] = (const float*)d_in[2 + 5 * m + 3];
        te[m] = (const float*)d_in[2 + 5 * m + 4];
    }
    char* ws = (char*)d_ws;
    int*   cnt     = (int*)ws;
    int*   nW      = (int*)(ws + 128);
    int*   work1   = (int*)(ws + 256);
    int*   work2   = (int*)(ws + 512);
    int*   toklist = (int*)(ws + 1024);
    float* H       = (float*)(ws + 66560);
    float* out     = (float*)d_out;

    bucket_kernel<<<1, 512, 0, stream>>>(ids, cnt, nW, work1, work2, toklist);
    layer1_kernel<<<dim3(48, 4), 256, 0, stream>>>(
        state, cnt, toklist, nW, work1,
        W1[0], W1[1], W1[2], W1[3],
        b1[0], b1[1], b1[2], b1[3], H);
    layer2_kernel<<<dim3(64, 4, 2), 256, 0, stream>>>(
        cnt, toklist, nW, work2, H,
        W2[0], W2[1], W2[2], W2[3],
        b2[0], b2[1], b2[2], b2[3],
        te[0], te[1], te[2], te[3], out);
}